// Round 6
// baseline (3291.088 us; speedup 1.0000x reference)
//
#include <hip/hip_runtime.h>
#include <hip/hip_bf16.h>
#include <stdint.h>

#define S_LEN 253
#define NHEAD 4
#define DHEAD 192
#define EPS_F 1e-5f

typedef __hip_bfloat16 bf16;
using short8  = __attribute__((ext_vector_type(8))) short;
using floatx4 = __attribute__((ext_vector_type(4))) float;
using half2_t = __attribute__((ext_vector_type(2))) _Float16;
typedef unsigned int u32;
typedef unsigned short u16;

__device__ inline float bf2f(bf16 v){ return __bfloat162float(v); }
__device__ inline bf16  f2bf(float v){ return __float2bfloat16(v); }
__device__ inline short f2bfs(float v){ bf16 b = __float2bfloat16(v); return __builtin_bit_cast(short, b); }
__device__ inline float us2f(u16 v){ u32 x = ((u32)v) << 16; return __builtin_bit_cast(float, x); }
__device__ inline half2_t h2(u32 v){ return __builtin_bit_cast(half2_t, v); }

__device__ inline void gll16(const void* g, void* l) {
  __builtin_amdgcn_global_load_lds((const __attribute__((address_space(1))) u32*)g,
                                   (__attribute__((address_space(3))) u32*)l, 16, 0, 0);
}

// packed f16 fma: 2 MACs/lane at full packed-math rate (v_pk_fma_f16)
__device__ inline half2_t pkfma(half2_t a, half2_t b, half2_t c){
  return __builtin_elementwise_fma(a, b, c);
}

// sum across the 4 lanes of a quad (lanes differing in bits 0..1), pure-VALU DPP
__device__ inline float quadsum(float x){
  int xi = __builtin_bit_cast(int, x);
  int a  = __builtin_amdgcn_update_dpp(0, xi, 0xB1, 0xF, 0xF, true);   // quad_perm [1,0,3,2]
  float s1 = x + __builtin_bit_cast(float, a);
  int si = __builtin_bit_cast(int, s1);
  int b  = __builtin_amdgcn_update_dpp(0, si, 0x4E, 0xF, 0xF, true);   // quad_perm [2,3,0,1]
  return s1 + __builtin_bit_cast(float, b);
}

// LDS-only barrier (builtin-only, verified r5): ds_write completion
// (lgkmcnt(0)) -> s_barrier. vmcnt is NOT drained.
// imm 0xC07F: vmcnt=63 (bits[3:0]=0xF,[15:14]=0x3), expcnt=7, lgkmcnt=0.
__device__ inline void lds_barrier(){
  __builtin_amdgcn_s_waitcnt(0xC07F);
  __builtin_amdgcn_s_barrier();
  __builtin_amdgcn_sched_barrier(0);
}

// ---------------- weight prep kernels (all inputs f32) ----------------
__global__ void prep_dayb(const float* __restrict__ db, const int* __restrict__ didx,
                          float* __restrict__ out) {
  int day = didx[0];
  int i = threadIdx.x + blockIdx.x*blockDim.x;
  if (i < 512) out[i] = db[day*512 + i];
}

// day_W[day] (512x512 f32, KxN) -> dayWT bf16 (NxK)
__global__ void transpose_day(const float* __restrict__ dayW, const int* __restrict__ didx,
                              bf16* __restrict__ out) {
  __shared__ float t[32][33];
  int day = didx[0];
  const float* in = dayW + (size_t)day*512*512;
  int c0 = blockIdx.x*32, r0 = blockIdx.y*32;
  int x = threadIdx.x, y = threadIdx.y;
  for (int dy=0; dy<32; dy+=8) t[y+dy][x] = in[(size_t)(r0+y+dy)*512 + c0+x];
  __syncthreads();
  for (int dy=0; dy<32; dy+=8) out[(size_t)(c0+y+dy)*512 + r0+x] = f2bf(t[x][y+dy]);
}

// in_proj_W (768x7168 f32, already NxK) -> bf16
__global__ void cvt_inW(const float* __restrict__ in, bf16* __restrict__ out) {
  size_t i = ((size_t)blockIdx.x*256 + threadIdx.x)*4;
  float4 v = *(const float4*)(in + i);
  out[i+0]=f2bf(v.x); out[i+1]=f2bf(v.y); out[i+2]=f2bf(v.z); out[i+3]=f2bf(v.w);
}

// gate_W (L,4,NH,192,192 f32) [d][e] -> gateWT bf16 [(l,h)][g*192+e][d]
__global__ void transpose_gate(const float* __restrict__ gw, bf16* __restrict__ out) {
  __shared__ float t[32][33];
  int z = blockIdx.z; int l = z>>4, g = (z>>2)&3, h = z&3;
  const float* in = gw + (size_t)z*(192*192);
  bf16* o = out + ((size_t)(l*4+h)*768 + g*192)*192;
  int e0 = blockIdx.x*32, d0 = blockIdx.y*32;
  int x = threadIdx.x, y = threadIdx.y;
  for (int dy=0; dy<32; dy+=8) t[y+dy][x] = in[(size_t)(d0+y+dy)*192 + e0+x];
  __syncthreads();
  for (int dy=0; dy<32; dy+=8) o[(size_t)(e0+y+dy)*192 + d0+x] = f2bf(t[x][y+dy]);
}

// rec_W (L,NH,192,768 f32) [d][(g,e)] -> recWT f16 [(l,h)][(g,e)][d]
__global__ void transpose_rec(const float* __restrict__ rw, _Float16* __restrict__ out) {
  __shared__ float t[32][33];
  int z = blockIdx.z;
  const float* in = rw + (size_t)z*(192*768);
  _Float16* o = out + (size_t)z*(768*192);
  int c0 = blockIdx.x*32, d0 = blockIdx.y*32;
  int x = threadIdx.x, y = threadIdx.y;
  for (int dy=0; dy<32; dy+=8) t[y+dy][x] = in[(size_t)(d0+y+dy)*768 + c0+x];
  __syncthreads();
  for (int dy=0; dy<32; dy+=8) o[(size_t)(c0+y+dy)*192 + d0+x] = (_Float16)t[x][y+dy];
}

// ---------------- GEMM (BT row-major NxK bf16) ----------------
// mode 0: day   (A = Af f32, staged via VALU convert; out bf16, bias f32, softsign)
// mode 1: inproj(A = bf16 patch view of x1 chunk; out f32, bias f32)
// mode 2: gates (A=xc/A2=xin bf16, col offset h*192; out bf16 to [(bl*4+h)][s][768])
__global__ __launch_bounds__(256, 2) void gemm_bt_kernel(
    const float* __restrict__ Af,
    const bf16* __restrict__ A, const bf16* __restrict__ A2, int lda,
    const bf16* __restrict__ BT,
    float* __restrict__ Cf, bf16* __restrict__ Cb,
    const float* __restrict__ biasf,
    int M, int N, int K, int mode)
{
  __shared__ __align__(16) short As[128*32];
  __shared__ __align__(16) short Bs[128*32];

  const int tid  = threadIdx.x;
  const int lane = tid & 63;
  const int wv   = tid >> 6;
  const int quad = lane >> 4;
  const int l16  = lane & 15;

  const int tile_m = blockIdx.x * 128;
  const int tile_n = blockIdx.y * 128;

  const bf16* Abase = A;
  const bf16* BTbase = BT;
  int coloff = 0, hsel = 0;
  if (mode == 2) {
    int z = blockIdx.z;
    hsel = z >> 1;
    int src = z & 1;
    Abase = (src ? A2 : A) + hsel * DHEAD;
    BTbase = BT + (size_t)hsel*(768*192) + (size_t)src*(384*192);
    coloff = src * 384;
  }

  auto arow = [&](int r)->const bf16* {   // bf16 A row (modes 1,2)
    r = min(r, M-1);
    if (mode == 1) { int b = r / S_LEN; int s = r - b*S_LEN;
                     return Abase + (size_t)b*(1024*512) + (size_t)s*2048; }
    return Abase + (size_t)r * lda;
  };

  const bf16  *aptr0=nullptr, *aptr1=nullptr;
  const float *fptr0=nullptr, *fptr1=nullptr;
  if (mode == 0) {
    fptr0 = Af + (size_t)min(tile_m + (tid>>2), M-1)*K + (tid&3)*8;
    fptr1 = Af + (size_t)min(tile_m + 64 + (tid>>2), M-1)*K + (tid&3)*8;
  } else {
    aptr0 = arow(tile_m + (tid>>2)) + (tid&3)*8;
    aptr1 = arow(tile_m + 64 + (tid>>2)) + (tid&3)*8;
  }
  const bf16* bptr0 = BTbase + (size_t)min(tile_n + (tid>>2), N-1)*K + (tid&3)*8;
  const bf16* bptr1 = BTbase + (size_t)min(tile_n + 64 + (tid>>2), N-1)*K + (tid&3)*8;

  short* As0 = As + wv*512;        short* As1 = As + 2048 + wv*512;
  short* Bs0 = Bs + wv*512;        short* Bs1 = Bs + 2048 + wv*512;

  floatx4 acc[4][4];
  #pragma unroll
  for (int i=0;i<4;i++)
    #pragma unroll
    for (int j=0;j<4;j++) acc[i][j] = (floatx4)0.0f;

  const int wm = wv & 1, wn = wv >> 1;
  const int aoff = (wm*64 + l16)*32 + quad*8;
  const int boff = (wn*64 + l16)*32 + quad*8;

  for (int k0 = 0; k0 < K; k0 += 32) {
    if (mode == 0) {
      float4 u0 = *(const float4*)(fptr0 + k0);
      float4 u1 = *(const float4*)(fptr0 + k0 + 4);
      float4 v0 = *(const float4*)(fptr1 + k0);
      float4 v1 = *(const float4*)(fptr1 + k0 + 4);
      short8 sa, sb;
      sa[0]=f2bfs(u0.x); sa[1]=f2bfs(u0.y); sa[2]=f2bfs(u0.z); sa[3]=f2bfs(u0.w);
      sa[4]=f2bfs(u1.x); sa[5]=f2bfs(u1.y); sa[6]=f2bfs(u1.z); sa[7]=f2bfs(u1.w);
      sb[0]=f2bfs(v0.x); sb[1]=f2bfs(v0.y); sb[2]=f2bfs(v0.z); sb[3]=f2bfs(v0.w);
      sb[4]=f2bfs(v1.x); sb[5]=f2bfs(v1.y); sb[6]=f2bfs(v1.z); sb[7]=f2bfs(v1.w);
      *(short8*)(As0 + lane*8) = sa;
      *(short8*)(As1 + lane*8) = sb;
    } else {
      gll16(aptr0 + k0, As0);
      gll16(aptr1 + k0, As1);
    }
    gll16(bptr0 + k0, Bs0);
    gll16(bptr1 + k0, Bs1);
    __syncthreads();
    short8 af[4], bfg[4];
    #pragma unroll
    for (int i=0;i<4;i++) af[i]  = *(const short8*)(As + aoff + i*512);
    #pragma unroll
    for (int j=0;j<4;j++) bfg[j] = *(const short8*)(Bs + boff + j*512);
    #pragma unroll
    for (int i=0;i<4;i++)
      #pragma unroll
      for (int j=0;j<4;j++)
        acc[i][j] = __builtin_amdgcn_mfma_f32_16x16x32_bf16(af[i], bfg[j], acc[i][j], 0,0,0);
    __syncthreads();
  }

  #pragma unroll
  for (int i=0;i<4;i++) {
    int m0 = tile_m + wm*64 + i*16 + quad*4;
    #pragma unroll
    for (int j=0;j<4;j++) {
      int n = tile_n + wn*64 + j*16 + l16;
      if (n >= N) continue;
      #pragma unroll
      for (int r=0;r<4;r++) {
        int row = m0 + r;
        if (row >= M) continue;
        float v = acc[i][j][r];
        if (mode == 0) {
          v += biasf[n];
          v = v / (1.0f + fabsf(v));
          Cb[(size_t)row * N + n] = f2bf(v);
        } else if (mode == 1) {
          v += biasf[n];
          Cf[(size_t)row * N + n] = v;
        } else {
          int bl = row / S_LEN, s = row - bl*S_LEN;
          Cb[((size_t)(bl*NHEAD + hsel)*S_LEN + s)*768 + coloff + n] = f2bf(v);
        }
      }
    }
  }
}

// ---------------- per-row LayerNorm -> bf16 (w f32) ----------------
__global__ __launch_bounds__(256) void ln_kernel(const float* __restrict__ x,
    const float* __restrict__ w, bf16* __restrict__ out) {
  int row = blockIdx.x, t = threadIdx.x;
  const float* xr = x + (size_t)row*768;
  float v[3]; float s = 0, sq = 0;
  #pragma unroll
  for (int i=0;i<3;i++){ v[i] = xr[t + i*256]; s += v[i]; sq += v[i]*v[i]; }
  __shared__ float rs[4], rq[4];
  for (int off=32; off>0; off>>=1){ s += __shfl_down(s,off); sq += __shfl_down(sq,off); }
  if ((t&63)==0){ rs[t>>6]=s; rq[t>>6]=sq; }
  __syncthreads();
  float s4 = rs[0]+rs[1]+rs[2]+rs[3], q4 = rq[0]+rq[1]+rq[2]+rq[3];
  float mu = s4/768.0f, var = q4/768.0f - mu*mu, inv = rsqrtf(var + EPS_F);
  #pragma unroll
  for (int i=0;i<3;i++){ int c = t + i*256;
    out[(size_t)row*768 + c] = f2bf((v[i]-mu)*inv*w[c]); }
}

// ---------------- causal depthwise conv K=4 + SiLU (W,b f32) ----------------
__global__ __launch_bounds__(256) void conv_kernel(const bf16* __restrict__ xin,
    const float* __restrict__ W, const float* __restrict__ bias, bf16* __restrict__ out) {
  int row = blockIdx.x; int b = row / S_LEN; int s = row - b*S_LEN;
  int t = threadIdx.x;
  #pragma unroll
  for (int i=0;i<3;i++){
    int d = t + i*256;
    float acc = bias[d];
    #pragma unroll
    for (int k=0;k<4;k++){
      int ss = s - 3 + k;
      if (ss >= 0) acc += W[d*4+k] * bf2f(xin[((size_t)b*S_LEN + ss)*768 + d]);
    }
    float sg = 1.0f/(1.0f + __expf(-acc));
    out[(size_t)row*768 + d] = f2bf(acc * sg);
  }
}

// ---------------- sLSTM scan v4d: quad-split, packed-f16 FMA dot engine ------
// One block per (bl,h), 768 threads (12 waves). Lane map within a wave:
//   q = lane&3  : dot-product chunk, covers h[48q .. 48q+48)
//   r = lane>>2 : e-slot, e = w*16 + r  (wave w covers e in [16w,16w+16))
// Lane (q,r) holds R chunks for the 4 gate columns {g*192+e}. The 48-deep
// partial dot per gate runs as TWO independent 12-deep v_pk_fma_f16 chains
// (f16 accumulation, <=24 terms/slot), combined in f32, then a quad DPP
// butterfly completes all four gate raws in-register (i,f,z,o).
// Rationale (r6): v_dot2_f32_f16 measured consistent with quarter-rate issue;
// v_pk_fma_f16 is full packed rate with identical instruction count.
__global__ __launch_bounds__(768, 1) void scan_kernel(
    const bf16* __restrict__ gates, const _Float16* __restrict__ recWT,
    const float* __restrict__ cellb, bf16* __restrict__ y)
{
  const int bh = blockIdx.x; const int bl = bh >> 2, h = bh & 3;
  const int tid  = threadIdx.x;
  const int w    = tid >> 6;
  const int lane = tid & 63;
  const int q    = lane & 3;
  const int r    = lane >> 2;
  const int e    = w*16 + r;
  const int nl   = q*192 + e;          // column whose gate/bias this lane injects

  // R fragments: for g=0..3, chunk q (48 f16) of column g*192+e -> 24 u32 each
  u32 Rc[4][24];
  {
    const _Float16* rbase = recWT + (size_t)h*768*192;
    #pragma unroll
    for (int g=0; g<4; g++){
      const uint4* rp = (const uint4*)(rbase + (size_t)(g*192 + e)*192 + q*48);
      #pragma unroll
      for (int j=0;j<6;j++){ uint4 v = rp[j];
        Rc[g][4*j]=v.x; Rc[g][4*j+1]=v.y; Rc[g][4*j+2]=v.z; Rc[g][4*j+3]=v.w; }
    }
  }
  const float bias = cellb[h*768 + nl];
  const bf16* gb = gates + (size_t)bh*S_LEN*768 + nl;

  __shared__ __align__(16) _Float16 hbuf[2][192];
  if (tid < 96) ((u32*)&hbuf[0][0])[tid] = 0;

  float cst = 0.0f, nst = 0.0f, mst = 0.0f;
  float ga = us2f(*(const u16*)gb);
  __syncthreads();

  for (int s = 0; s < S_LEN; s++) {
    float inj = ga + bias;
    if (s + 1 < S_LEN) ga = us2f(*(const u16*)(gb + (size_t)(s+1)*768));

    const half2_t hz2 = (half2_t)(_Float16)0.0f;
    half2_t pa0=hz2, pb0=hz2, pa1=hz2, pb1=hz2;
    half2_t pa2=hz2, pb2=hz2, pa3=hz2, pb3=hz2;

    const uint4* hb = (const uint4*)((const char*)&hbuf[s & 1][0] + q*96);
    #pragma unroll
    for (int j=0;j<6;j++) {
      uint4 hv = hb[j];
      half2_t hx = h2(hv.x), hy = h2(hv.y), hz = h2(hv.z), hw = h2(hv.w);
      pa0 = pkfma(hx, h2(Rc[0][4*j+0]), pa0);
      pa0 = pkfma(hy, h2(Rc[0][4*j+1]), pa0);
      pb0 = pkfma(hz, h2(Rc[0][4*j+2]), pb0);
      pb0 = pkfma(hw, h2(Rc[0][4*j+3]), pb0);
      pa1 = pkfma(hx, h2(Rc[1][4*j+0]), pa1);
      pa1 = pkfma(hy, h2(Rc[1][4*j+1]), pa1);
      pb1 = pkfma(hz, h2(Rc[1][4*j+2]), pb1);
      pb1 = pkfma(hw, h2(Rc[1][4*j+3]), pb1);
      pa2 = pkfma(hx, h2(Rc[2][4*j+0]), pa2);
      pa2 = pkfma(hy, h2(Rc[2][4*j+1]), pa2);
      pb2 = pkfma(hz, h2(Rc[2][4*j+2]), pb2);
      pb2 = pkfma(hw, h2(Rc[2][4*j+3]), pb2);
      pa3 = pkfma(hx, h2(Rc[3][4*j+0]), pa3);
      pa3 = pkfma(hy, h2(Rc[3][4*j+1]), pa3);
      pb3 = pkfma(hz, h2(Rc[3][4*j+2]), pb3);
      pb3 = pkfma(hw, h2(Rc[3][4*j+3]), pb3);
    }

    // combine the f16 partial sums in f32, injection included
    float p0 = (q==0) ? inj : 0.0f;
    float p1 = (q==1) ? inj : 0.0f;
    float p2 = (q==2) ? inj : 0.0f;
    float p3 = (q==3) ? inj : 0.0f;
    { half2_t s0 = pa0 + pb0; p0 += (float)s0[0] + (float)s0[1]; }
    { half2_t s1 = pa1 + pb1; p1 += (float)s1[0] + (float)s1[1]; }
    { half2_t s2 = pa2 + pb2; p2 += (float)s2[0] + (float)s2[1]; }
    { half2_t s3 = pa3 + pb3; p3 += (float)s3[0] + (float)s3[1]; }

    // complete the 192-deep dots across the quad; afterwards every lane of the
    // quad holds all four gate raws for its e (i,f,z,o).
    float iraw = quadsum(p0);
    float fraw = quadsum(p1);
    float zraw = quadsum(p2);
    float oraw = quadsum(p3);

    float lsig = fminf(fraw, 0.0f) - log1pf(__expf(-fabsf(fraw)));
    float lfpm = mst + lsig;
    float mnew = (s == 0) ? iraw : fmaxf(iraw, lfpm);
    float ig = __expf(iraw - mnew);
    float e2z = __expf(2.0f * zraw);
    float tz = 1.0f - 2.0f/(e2z + 1.0f);
    float cnew, nnew;
    if (s == 0) { cnew = ig*tz; nnew = ig; }
    else {
      float fg = __expf(lfpm - mnew);
      cnew = fg*cst + ig*tz; nnew = fg*nst + ig;
    }
    float sg = 1.0f/(1.0f + __expf(-oraw));
    float yv = sg * cnew / nnew;
    cst = cnew; nst = nnew; mst = mnew;

    if (q == 0) {
      hbuf[(s+1)&1][e] = (_Float16)yv;
      y[((size_t)bl*S_LEN + s)*768 + h*DHEAD + e] = f2bf(yv);
    }
    lds_barrier();
  }
}

// ---------------- GroupNorm over DH + residual into x (y bf16, w f32) ----------------
__global__ __launch_bounds__(64) void gn_kernel(const bf16* __restrict__ y,
    const float* __restrict__ w, float* __restrict__ x) {
  int rg = blockIdx.x;
  int row = rg >> 2, h = rg & 3;
  int t = threadIdx.x;
  const bf16* yr = y + (size_t)row*768 + h*DHEAD;
  float v0 = bf2f(yr[t]), v1 = bf2f(yr[t+64]), v2 = bf2f(yr[t+128]);
  float s = v0+v1+v2, sq = v0*v0+v1*v1+v2*v2;
  for (int off=32; off>0; off>>=1){ s += __shfl_down(s,off); sq += __shfl_down(sq,off); }
  s = __shfl(s, 0); sq = __shfl(sq, 0);
  float mu = s/192.0f, var = sq/192.0f - mu*mu, inv = rsqrtf(var + EPS_F);
  float* xr = x + (size_t)row*768 + h*DHEAD;
  xr[t]     += (v0-mu)*inv*w[h*DHEAD+t];
  xr[t+64]  += (v1-mu)*inv*w[h*DHEAD+t+64];
  xr[t+128] += (v2-mu)*inv*w[h*DHEAD+t+128];
}

// ---------------- post-LN + out projection (N=41), all f32 ----------------
__global__ __launch_bounds__(256) void out_kernel(const float* __restrict__ x,
    const float* __restrict__ lnw, const float* __restrict__ outW,
    const float* __restrict__ outb, float* __restrict__ out) {
  __shared__ float xn[768];
  __shared__ float red[8];
  __shared__ float pb[41][6];
  int row = blockIdx.x, t = threadIdx.x;
  const float* xr = x + (size_t)row*768;
  float v[3]; float s = 0, sq = 0;
  #pragma unroll
  for (int i=0;i<3;i++){ v[i]=xr[t+i*256]; s+=v[i]; sq+=v[i]*v[i]; }
  for (int off=32; off>0; off>>=1){ s+=__shfl_down(s,off); sq+=__shfl_down(sq,off); }
  if ((t&63)==0){ red[t>>6]=s; red[4+(t>>6)]=sq; }
  __syncthreads();
  float s4=red[0]+red[1]+red[2]+red[3], q4=red[4]+red[5]+red[6]+red[7];
  float mu=s4/768.0f, var=q4/768.0f-mu*mu, inv=rsqrtf(var+EPS_F);
  #pragma unroll
  for (int i=0;i<3;i++){ int cc=t+i*256; xn[cc]=(v[i]-mu)*inv*lnw[cc]; }
  __syncthreads();
  if (t < 246) {
    int cls = t / 6, ch = t % 6;
    const float* wr = outW + (size_t)cls*768 + ch*128;
    const float* xp = xn + ch*128;
    float a = 0;
    for (int k=0;k<128;k++) a += xp[k]*wr[k];
    pb[cls][ch] = a;
  }
  __syncthreads();
  if (t < 41) {
    float a = outb[t];
    #pragma unroll
    for (int ch=0; ch<6; ch++) a += pb[t][ch];
    out[(size_t)row*41 + t] = a;
  }
}

extern "C" void kernel_launch(void* const* d_in, const int* in_sizes, int n_in,
                              void* d_out, int out_size, void* d_ws, size_t ws_size,
                              hipStream_t stream) {
  const float* features = (const float*)d_in[0];
  const int*   didx     = (const int*)d_in[1];
  const float* dayW     = (const float*)d_in[2];
  const float* dayb     = (const float*)d_in[3];
  const float* inW      = (const float*)d_in[4];
  const float* inb      = (const float*)d_in[5];
  const float* lnw      = (const float*)d_in[6];
  const float* convW    = (const float*)d_in[7];
  const float* convb    = (const float*)d_in[8];
  const float* gateW    = (const float*)d_in[9];
  const float* recW     = (const float*)d_in[10];
  const float* cellb    = (const float*)d_in[11];
  const float* gnw      = (const float*)d_in[12];
  const float* plnw     = (const float*)d_in[13];
  const float* outW     = (const float*)d_in[14];
  const float* outb     = (const float*)d_in[15];
  float* out = (float*)d_out;

  auto AL = [](size_t v)->size_t { return (v + 255) & ~255ULL; };

  // persistent buffers
  const size_t GATEWT_B = (size_t)5*4*768*192*2;   // 5.9 MB
  const size_t RECWT_B  = (size_t)20*768*192*2;    // 5.9 MB
  const size_t X_B      = (size_t)8096*768*4;      // 24.9 MB
  const size_t PERSIST  = AL(GATEWT_B) + AL(RECWT_B) + AL(X_B) + AL(2048);

  // choose chunking: merged (1 chunk of 32 batches) if workspace allows,
  // else the verified 2x16 layout (~80.2 MB).
  int nch = 2, bch = 16;
  {
    const size_t uPreM  = AL((size_t)512*512*2) + AL((size_t)768*7168*2)
                        + AL((size_t)32*1024*512*2);
    const size_t xinM   = AL((size_t)32*S_LEN*768*2);
    const size_t uLoopM = xinM*2 + AL((size_t)32*4*S_LEN*768*2) + xinM;
    const size_t uMaxM  = uPreM > uLoopM ? uPreM : uLoopM;
    if (ws_size >= PERSIST + uMaxM + 4096) { nch = 1; bch = 32; }
  }
  const int MCH = bch * S_LEN;              // rows per chunk

  char* ws = (char*)d_ws;
  size_t off = 0;
  auto alloc = [&](size_t bytes)->void* { void* p = ws + off; off += AL(bytes); return p; };
  bf16*     gateWT = (bf16*)alloc(GATEWT_B);
  _Float16* recWT  = (_Float16*)alloc(RECWT_B);
  float*    x      = (float*)alloc(X_B);
  float*    dbsel  = (float*)alloc(2048);
  char*     U      = ws + off;
  // pre-loop carve of U:
  bf16*     dayWT  = (bf16*)U;
  bf16*     inWT   = (bf16*)(U + AL((size_t)512*512*2));
  bf16*     x1     = (bf16*)(U + AL((size_t)512*512*2) + AL((size_t)768*7168*2));
  // loop carve of U:
  const size_t xinB  = (size_t)MCH*768*2;
  const size_t gbufB = (size_t)bch*4*S_LEN*768*2;
  bf16*     xin    = (bf16*)U;
  bf16*     xc     = (bf16*)(U + AL(xinB));
  bf16*     gbuf   = (bf16*)(U + AL(xinB) + AL(xinB));
  bf16*     ybuf   = (bf16*)(U + AL(xinB) + AL(xinB) + AL(gbufB));

  prep_dayb<<<dim3(2), dim3(256), 0, stream>>>(dayb, didx, dbsel);
  transpose_day<<<dim3(16,16), dim3(32,8), 0, stream>>>(dayW, didx, dayWT);
  cvt_inW<<<dim3(5376), dim3(256), 0, stream>>>(inW, inWT);
  transpose_gate<<<dim3(6,6,80), dim3(32,8), 0, stream>>>(gateW, gateWT);
  transpose_rec<<<dim3(24,6,20), dim3(32,8), 0, stream>>>(recW, recWT);

  // day projection + softsign + in_proj, batch-chunked (x1 holds bch batches)
  for (int c = 0; c < nch; c++) {
    gemm_bt_kernel<<<dim3(bch*8, 4, 1), dim3(256), 0, stream>>>(
        features + (size_t)c*bch*1024*512, (const bf16*)nullptr, (const bf16*)nullptr, 512, dayWT,
        (float*)nullptr, x1, dbsel, bch*1024, 512, 512, 0);
    gemm_bt_kernel<<<dim3((MCH+127)/128, 6, 1), dim3(256), 0, stream>>>(
        (const float*)nullptr, x1, (const bf16*)nullptr, 0, inWT,
        x + (size_t)c*MCH*768, (bf16*)nullptr, inb, MCH, 768, 7168, 1);
  }

  for (int l = 0; l < 5; l++) {
    for (int c = 0; c < nch; c++) {
      float* xC = x + (size_t)c*MCH*768;
      ln_kernel  <<<dim3(MCH), dim3(256), 0, stream>>>(xC, lnw + (size_t)l*768, xin);
      conv_kernel<<<dim3(MCH), dim3(256), 0, stream>>>(xin, convW + (size_t)l*768*4, convb + (size_t)l*768, xc);
      gemm_bt_kernel<<<dim3((MCH+127)/128, 3, 8), dim3(256), 0, stream>>>(
          (const float*)nullptr, xc, xin, 768, gateWT + (size_t)l*4*768*192,
          (float*)nullptr, gbuf, (const float*)nullptr, MCH, 384, 192, 2);
      scan_kernel<<<dim3(bch*NHEAD), dim3(768), 0, stream>>>(
          gbuf, recWT + (size_t)l*4*768*192, cellb + (size_t)l*3072, ybuf);
      gn_kernel  <<<dim3(MCH*NHEAD), dim3(64), 0, stream>>>(ybuf, gnw + (size_t)l*768, xC);
    }
  }
  out_kernel<<<dim3(8096), dim3(256), 0, stream>>>(x, plnw, outW, outb, out);
}

// Round 7
// 3107.310 us; speedup vs baseline: 1.0591x; 1.0591x over previous
//
#include <hip/hip_runtime.h>
#include <hip/hip_bf16.h>
#include <stdint.h>

#define S_LEN 253
#define NHEAD 4
#define DHEAD 192
#define EPS_F 1e-5f

typedef __hip_bfloat16 bf16;
using short8  = __attribute__((ext_vector_type(8))) short;
using floatx4 = __attribute__((ext_vector_type(4))) float;
using half2_t = __attribute__((ext_vector_type(2))) _Float16;
typedef unsigned int u32;
typedef unsigned short u16;

__device__ inline float bf2f(bf16 v){ return __bfloat162float(v); }
__device__ inline bf16  f2bf(float v){ return __float2bfloat16(v); }
__device__ inline short f2bfs(float v){ bf16 b = __float2bfloat16(v); return __builtin_bit_cast(short, b); }
__device__ inline float us2f(u16 v){ u32 x = ((u32)v) << 16; return __builtin_bit_cast(float, x); }
__device__ inline half2_t h2(u32 v){ return __builtin_bit_cast(half2_t, v); }

__device__ inline void gll16(const void* g, void* l) {
  __builtin_amdgcn_global_load_lds((const __attribute__((address_space(1))) u32*)g,
                                   (__attribute__((address_space(3))) u32*)l, 16, 0, 0);
}

__device__ inline float fdot2(half2_t a, half2_t b, float c) {
#if __has_builtin(__builtin_amdgcn_fdot2)
  return __builtin_amdgcn_fdot2(a, b, c, false);
#else
  return c + (float)a[0]*(float)b[0] + (float)a[1]*(float)b[1];
#endif
}

// sum across the 4 lanes of a quad (lanes differing in bits 0..1), pure-VALU DPP
__device__ inline float quadsum(float x){
  int xi = __builtin_bit_cast(int, x);
  int a  = __builtin_amdgcn_update_dpp(0, xi, 0xB1, 0xF, 0xF, true);   // quad_perm [1,0,3,2]
  float s1 = x + __builtin_bit_cast(float, a);
  int si = __builtin_bit_cast(int, s1);
  int b  = __builtin_amdgcn_update_dpp(0, si, 0x4E, 0xF, 0xF, true);   // quad_perm [2,3,0,1]
  return s1 + __builtin_bit_cast(float, b);
}

// LDS-only barrier (builtin-only, verified r5): ds_write completion
// (lgkmcnt(0)) -> s_barrier. vmcnt is NOT drained.
// imm 0xC07F: vmcnt=63 (bits[3:0]=0xF,[15:14]=0x3), expcnt=7, lgkmcnt=0.
__device__ inline void lds_barrier(){
  __builtin_amdgcn_s_waitcnt(0xC07F);
  __builtin_amdgcn_s_barrier();
  __builtin_amdgcn_sched_barrier(0);
}

// ---------------- weight prep kernels (all inputs f32) ----------------
__global__ void prep_dayb(const float* __restrict__ db, const int* __restrict__ didx,
                          float* __restrict__ out) {
  int day = didx[0];
  int i = threadIdx.x + blockIdx.x*blockDim.x;
  if (i < 512) out[i] = db[day*512 + i];
}

// day_W[day] (512x512 f32, KxN) -> dayWT bf16 (NxK)
__global__ void transpose_day(const float* __restrict__ dayW, const int* __restrict__ didx,
                              bf16* __restrict__ out) {
  __shared__ float t[32][33];
  int day = didx[0];
  const float* in = dayW + (size_t)day*512*512;
  int c0 = blockIdx.x*32, r0 = blockIdx.y*32;
  int x = threadIdx.x, y = threadIdx.y;
  for (int dy=0; dy<32; dy+=8) t[y+dy][x] = in[(size_t)(r0+y+dy)*512 + c0+x];
  __syncthreads();
  for (int dy=0; dy<32; dy+=8) out[(size_t)(c0+y+dy)*512 + r0+x] = f2bf(t[x][y+dy]);
}

// in_proj_W (768x7168 f32, already NxK) -> bf16
__global__ void cvt_inW(const float* __restrict__ in, bf16* __restrict__ out) {
  size_t i = ((size_t)blockIdx.x*256 + threadIdx.x)*4;
  float4 v = *(const float4*)(in + i);
  out[i+0]=f2bf(v.x); out[i+1]=f2bf(v.y); out[i+2]=f2bf(v.z); out[i+3]=f2bf(v.w);
}

// gate_W (L,4,NH,192,192 f32) [d][e] -> gateWT bf16 [(l,h)][g*192+e][d]
__global__ void transpose_gate(const float* __restrict__ gw, bf16* __restrict__ out) {
  __shared__ float t[32][33];
  int z = blockIdx.z; int l = z>>4, g = (z>>2)&3, h = z&3;
  const float* in = gw + (size_t)z*(192*192);
  bf16* o = out + ((size_t)(l*4+h)*768 + g*192)*192;
  int e0 = blockIdx.x*32, d0 = blockIdx.y*32;
  int x = threadIdx.x, y = threadIdx.y;
  for (int dy=0; dy<32; dy+=8) t[y+dy][x] = in[(size_t)(d0+y+dy)*192 + e0+x];
  __syncthreads();
  for (int dy=0; dy<32; dy+=8) o[(size_t)(e0+y+dy)*192 + d0+x] = f2bf(t[x][y+dy]);
}

// rec_W (L,NH,192,768 f32) [d][(g,e)] -> recWT f16 [(l,h)][(g,e)][d]
__global__ void transpose_rec(const float* __restrict__ rw, _Float16* __restrict__ out) {
  __shared__ float t[32][33];
  int z = blockIdx.z;
  const float* in = rw + (size_t)z*(192*768);
  _Float16* o = out + (size_t)z*(768*192);
  int c0 = blockIdx.x*32, d0 = blockIdx.y*32;
  int x = threadIdx.x, y = threadIdx.y;
  for (int dy=0; dy<32; dy+=8) t[y+dy][x] = in[(size_t)(d0+y+dy)*768 + c0+x];
  __syncthreads();
  for (int dy=0; dy<32; dy+=8) o[(size_t)(c0+y+dy)*192 + d0+x] = (_Float16)t[x][y+dy];
}

// ---------------- GEMM (BT row-major NxK bf16) ----------------
// mode 0: day   (A = Af f32, staged via VALU convert; out bf16, bias f32, softsign)
// mode 1: inproj(A = bf16 patch view of x1 chunk; out f32, bias f32)
// mode 2: gates (A=xc/A2=xin bf16, col offset h*192; out bf16 to [(bl*4+h)][s][768])
__global__ __launch_bounds__(256, 2) void gemm_bt_kernel(
    const float* __restrict__ Af,
    const bf16* __restrict__ A, const bf16* __restrict__ A2, int lda,
    const bf16* __restrict__ BT,
    float* __restrict__ Cf, bf16* __restrict__ Cb,
    const float* __restrict__ biasf,
    int M, int N, int K, int mode)
{
  __shared__ __align__(16) short As[128*32];
  __shared__ __align__(16) short Bs[128*32];

  const int tid  = threadIdx.x;
  const int lane = tid & 63;
  const int wv   = tid >> 6;
  const int quad = lane >> 4;
  const int l16  = lane & 15;

  const int tile_m = blockIdx.x * 128;
  const int tile_n = blockIdx.y * 128;

  const bf16* Abase = A;
  const bf16* BTbase = BT;
  int coloff = 0, hsel = 0;
  if (mode == 2) {
    int z = blockIdx.z;
    hsel = z >> 1;
    int src = z & 1;
    Abase = (src ? A2 : A) + hsel * DHEAD;
    BTbase = BT + (size_t)hsel*(768*192) + (size_t)src*(384*192);
    coloff = src * 384;
  }

  auto arow = [&](int r)->const bf16* {   // bf16 A row (modes 1,2)
    r = min(r, M-1);
    if (mode == 1) { int b = r / S_LEN; int s = r - b*S_LEN;
                     return Abase + (size_t)b*(1024*512) + (size_t)s*2048; }
    return Abase + (size_t)r * lda;
  };

  const bf16  *aptr0=nullptr, *aptr1=nullptr;
  const float *fptr0=nullptr, *fptr1=nullptr;
  if (mode == 0) {
    fptr0 = Af + (size_t)min(tile_m + (tid>>2), M-1)*K + (tid&3)*8;
    fptr1 = Af + (size_t)min(tile_m + 64 + (tid>>2), M-1)*K + (tid&3)*8;
  } else {
    aptr0 = arow(tile_m + (tid>>2)) + (tid&3)*8;
    aptr1 = arow(tile_m + 64 + (tid>>2)) + (tid&3)*8;
  }
  const bf16* bptr0 = BTbase + (size_t)min(tile_n + (tid>>2), N-1)*K + (tid&3)*8;
  const bf16* bptr1 = BTbase + (size_t)min(tile_n + 64 + (tid>>2), N-1)*K + (tid&3)*8;

  short* As0 = As + wv*512;        short* As1 = As + 2048 + wv*512;
  short* Bs0 = Bs + wv*512;        short* Bs1 = Bs + 2048 + wv*512;

  floatx4 acc[4][4];
  #pragma unroll
  for (int i=0;i<4;i++)
    #pragma unroll
    for (int j=0;j<4;j++) acc[i][j] = (floatx4)0.0f;

  const int wm = wv & 1, wn = wv >> 1;
  const int aoff = (wm*64 + l16)*32 + quad*8;
  const int boff = (wn*64 + l16)*32 + quad*8;

  for (int k0 = 0; k0 < K; k0 += 32) {
    if (mode == 0) {
      float4 u0 = *(const float4*)(fptr0 + k0);
      float4 u1 = *(const float4*)(fptr0 + k0 + 4);
      float4 v0 = *(const float4*)(fptr1 + k0);
      float4 v1 = *(const float4*)(fptr1 + k0 + 4);
      short8 sa, sb;
      sa[0]=f2bfs(u0.x); sa[1]=f2bfs(u0.y); sa[2]=f2bfs(u0.z); sa[3]=f2bfs(u0.w);
      sa[4]=f2bfs(u1.x); sa[5]=f2bfs(u1.y); sa[6]=f2bfs(u1.z); sa[7]=f2bfs(u1.w);
      sb[0]=f2bfs(v0.x); sb[1]=f2bfs(v0.y); sb[2]=f2bfs(v0.z); sb[3]=f2bfs(v0.w);
      sb[4]=f2bfs(v1.x); sb[5]=f2bfs(v1.y); sb[6]=f2bfs(v1.z); sb[7]=f2bfs(v1.w);
      *(short8*)(As0 + lane*8) = sa;
      *(short8*)(As1 + lane*8) = sb;
    } else {
      gll16(aptr0 + k0, As0);
      gll16(aptr1 + k0, As1);
    }
    gll16(bptr0 + k0, Bs0);
    gll16(bptr1 + k0, Bs1);
    __syncthreads();
    short8 af[4], bfg[4];
    #pragma unroll
    for (int i=0;i<4;i++) af[i]  = *(const short8*)(As + aoff + i*512);
    #pragma unroll
    for (int j=0;j<4;j++) bfg[j] = *(const short8*)(Bs + boff + j*512);
    #pragma unroll
    for (int i=0;i<4;i++)
      #pragma unroll
      for (int j=0;j<4;j++)
        acc[i][j] = __builtin_amdgcn_mfma_f32_16x16x32_bf16(af[i], bfg[j], acc[i][j], 0,0,0);
    __syncthreads();
  }

  #pragma unroll
  for (int i=0;i<4;i++) {
    int m0 = tile_m + wm*64 + i*16 + quad*4;
    #pragma unroll
    for (int j=0;j<4;j++) {
      int n = tile_n + wn*64 + j*16 + l16;
      if (n >= N) continue;
      #pragma unroll
      for (int r=0;r<4;r++) {
        int row = m0 + r;
        if (row >= M) continue;
        float v = acc[i][j][r];
        if (mode == 0) {
          v += biasf[n];
          v = v / (1.0f + fabsf(v));
          Cb[(size_t)row * N + n] = f2bf(v);
        } else if (mode == 1) {
          v += biasf[n];
          Cf[(size_t)row * N + n] = v;
        } else {
          int bl = row / S_LEN, s = row - bl*S_LEN;
          Cb[((size_t)(bl*NHEAD + hsel)*S_LEN + s)*768 + coloff + n] = f2bf(v);
        }
      }
    }
  }
}

// ---------------- per-row LayerNorm -> bf16 (w f32) ----------------
__global__ __launch_bounds__(256) void ln_kernel(const float* __restrict__ x,
    const float* __restrict__ w, bf16* __restrict__ out) {
  int row = blockIdx.x, t = threadIdx.x;
  const float* xr = x + (size_t)row*768;
  float v[3]; float s = 0, sq = 0;
  #pragma unroll
  for (int i=0;i<3;i++){ v[i] = xr[t + i*256]; s += v[i]; sq += v[i]*v[i]; }
  __shared__ float rs[4], rq[4];
  for (int off=32; off>0; off>>=1){ s += __shfl_down(s,off); sq += __shfl_down(sq,off); }
  if ((t&63)==0){ rs[t>>6]=s; rq[t>>6]=sq; }
  __syncthreads();
  float s4 = rs[0]+rs[1]+rs[2]+rs[3], q4 = rq[0]+rq[1]+rq[2]+rq[3];
  float mu = s4/768.0f, var = q4/768.0f - mu*mu, inv = rsqrtf(var + EPS_F);
  #pragma unroll
  for (int i=0;i<3;i++){ int c = t + i*256;
    out[(size_t)row*768 + c] = f2bf((v[i]-mu)*inv*w[c]); }
}

// ---------------- causal depthwise conv K=4 + SiLU (W,b f32) ----------------
__global__ __launch_bounds__(256) void conv_kernel(const bf16* __restrict__ xin,
    const float* __restrict__ W, const float* __restrict__ bias, bf16* __restrict__ out) {
  int row = blockIdx.x; int b = row / S_LEN; int s = row - b*S_LEN;
  int t = threadIdx.x;
  #pragma unroll
  for (int i=0;i<3;i++){
    int d = t + i*256;
    float acc = bias[d];
    #pragma unroll
    for (int k=0;k<4;k++){
      int ss = s - 3 + k;
      if (ss >= 0) acc += W[d*4+k] * bf2f(xin[((size_t)b*S_LEN + ss)*768 + d]);
    }
    float sg = 1.0f/(1.0f + __expf(-acc));
    out[(size_t)row*768 + d] = f2bf(acc * sg);
  }
}

// ---------------- sLSTM scan v4e: quad-split + VGPR-resident R ---------------
// Identical to the verified v4c (r5) except __launch_bounds__(768, 3):
// a 12-wave block needs exactly 3 waves/SIMD, so the VGPR budget is 512/3=170.
// The default allocator targeted 64 VGPRs (2-block occupancy that never
// materializes with 128 blocks on 256 CUs) and spilled the 96-reg Rc array to
// scratch — the hidden per-step reload that dominated r0-r6 scan time.
__global__ __launch_bounds__(768, 3) void scan_kernel(
    const bf16* __restrict__ gates, const _Float16* __restrict__ recWT,
    const float* __restrict__ cellb, bf16* __restrict__ y)
{
  const int bh = blockIdx.x; const int bl = bh >> 2, h = bh & 3;
  const int tid  = threadIdx.x;
  const int w    = tid >> 6;
  const int lane = tid & 63;
  const int q    = lane & 3;
  const int r    = lane >> 2;
  const int e    = w*16 + r;
  const int nl   = q*192 + e;          // column whose gate/bias this lane injects

  // R fragments: for g=0..3, chunk q (48 f16) of column g*192+e -> 24 u32 each
  u32 Rc[4][24];
  {
    const _Float16* rbase = recWT + (size_t)h*768*192;
    #pragma unroll
    for (int g=0; g<4; g++){
      const uint4* rp = (const uint4*)(rbase + (size_t)(g*192 + e)*192 + q*48);
      #pragma unroll
      for (int j=0;j<6;j++){ uint4 v = rp[j];
        Rc[g][4*j]=v.x; Rc[g][4*j+1]=v.y; Rc[g][4*j+2]=v.z; Rc[g][4*j+3]=v.w; }
    }
  }
  const float bias = cellb[h*768 + nl];
  const bf16* gb = gates + (size_t)bh*S_LEN*768 + nl;

  __shared__ __align__(16) _Float16 hbuf[2][192];
  if (tid < 96) ((u32*)&hbuf[0][0])[tid] = 0;

  float cst = 0.0f, nst = 0.0f, mst = 0.0f;
  float ga = us2f(*(const u16*)gb);
  __syncthreads();

  for (int s = 0; s < S_LEN; s++) {
    float inj = ga + bias;
    if (s + 1 < S_LEN) ga = us2f(*(const u16*)(gb + (size_t)(s+1)*768));

    float p0 = (q==0) ? inj : 0.0f;
    float p1 = (q==1) ? inj : 0.0f;
    float p2 = (q==2) ? inj : 0.0f;
    float p3 = (q==3) ? inj : 0.0f;

    const uint4* hb = (const uint4*)((const char*)&hbuf[s & 1][0] + q*96);
    #pragma unroll
    for (int j=0;j<6;j++) {
      uint4 hv = hb[j];
      p0 = fdot2(h2(hv.x), h2(Rc[0][4*j+0]), p0);
      p0 = fdot2(h2(hv.y), h2(Rc[0][4*j+1]), p0);
      p0 = fdot2(h2(hv.z), h2(Rc[0][4*j+2]), p0);
      p0 = fdot2(h2(hv.w), h2(Rc[0][4*j+3]), p0);
      p1 = fdot2(h2(hv.x), h2(Rc[1][4*j+0]), p1);
      p1 = fdot2(h2(hv.y), h2(Rc[1][4*j+1]), p1);
      p1 = fdot2(h2(hv.z), h2(Rc[1][4*j+2]), p1);
      p1 = fdot2(h2(hv.w), h2(Rc[1][4*j+3]), p1);
      p2 = fdot2(h2(hv.x), h2(Rc[2][4*j+0]), p2);
      p2 = fdot2(h2(hv.y), h2(Rc[2][4*j+1]), p2);
      p2 = fdot2(h2(hv.z), h2(Rc[2][4*j+2]), p2);
      p2 = fdot2(h2(hv.w), h2(Rc[2][4*j+3]), p2);
      p3 = fdot2(h2(hv.x), h2(Rc[3][4*j+0]), p3);
      p3 = fdot2(h2(hv.y), h2(Rc[3][4*j+1]), p3);
      p3 = fdot2(h2(hv.z), h2(Rc[3][4*j+2]), p3);
      p3 = fdot2(h2(hv.w), h2(Rc[3][4*j+3]), p3);
    }

    // complete the 192-deep dots across the quad; afterwards every lane of the
    // quad holds all four gate raws for its e (i,f,z,o), injection included.
    float iraw = quadsum(p0);
    float fraw = quadsum(p1);
    float zraw = quadsum(p2);
    float oraw = quadsum(p3);

    float lsig = fminf(fraw, 0.0f) - log1pf(__expf(-fabsf(fraw)));
    float lfpm = mst + lsig;
    float mnew = (s == 0) ? iraw : fmaxf(iraw, lfpm);
    float ig = __expf(iraw - mnew);
    float e2z = __expf(2.0f * zraw);
    float tz = 1.0f - 2.0f/(e2z + 1.0f);
    float cnew, nnew;
    if (s == 0) { cnew = ig*tz; nnew = ig; }
    else {
      float fg = __expf(lfpm - mnew);
      cnew = fg*cst + ig*tz; nnew = fg*nst + ig;
    }
    float sg = 1.0f/(1.0f + __expf(-oraw));
    float yv = sg * cnew / nnew;
    cst = cnew; nst = nnew; mst = mnew;

    if (q == 0) {
      hbuf[(s+1)&1][e] = (_Float16)yv;
      y[((size_t)bl*S_LEN + s)*768 + h*DHEAD + e] = f2bf(yv);
    }
    lds_barrier();
  }
}

// ---------------- GroupNorm over DH + residual into x (y bf16, w f32) ----------------
__global__ __launch_bounds__(64) void gn_kernel(const bf16* __restrict__ y,
    const float* __restrict__ w, float* __restrict__ x) {
  int rg = blockIdx.x;
  int row = rg >> 2, h = rg & 3;
  int t = threadIdx.x;
  const bf16* yr = y + (size_t)row*768 + h*DHEAD;
  float v0 = bf2f(yr[t]), v1 = bf2f(yr[t+64]), v2 = bf2f(yr[t+128]);
  float s = v0+v1+v2, sq = v0*v0+v1*v1+v2*v2;
  for (int off=32; off>0; off>>=1){ s += __shfl_down(s,off); sq += __shfl_down(sq,off); }
  s = __shfl(s, 0); sq = __shfl(sq, 0);
  float mu = s/192.0f, var = sq/192.0f - mu*mu, inv = rsqrtf(var + EPS_F);
  float* xr = x + (size_t)row*768 + h*DHEAD;
  xr[t]     += (v0-mu)*inv*w[h*DHEAD+t];
  xr[t+64]  += (v1-mu)*inv*w[h*DHEAD+t+64];
  xr[t+128] += (v2-mu)*inv*w[h*DHEAD+t+128];
}

// ---------------- post-LN + out projection (N=41), all f32 ----------------
__global__ __launch_bounds__(256) void out_kernel(const float* __restrict__ x,
    const float* __restrict__ lnw, const float* __restrict__ outW,
    const float* __restrict__ outb, float* __restrict__ out) {
  __shared__ float xn[768];
  __shared__ float red[8];
  __shared__ float pb[41][6];
  int row = blockIdx.x, t = threadIdx.x;
  const float* xr = x + (size_t)row*768;
  float v[3]; float s = 0, sq = 0;
  #pragma unroll
  for (int i=0;i<3;i++){ v[i]=xr[t+i*256]; s+=v[i]; sq+=v[i]*v[i]; }
  for (int off=32; off>0; off>>=1){ s+=__shfl_down(s,off); sq+=__shfl_down(sq,off); }
  if ((t&63)==0){ red[t>>6]=s; red[4+(t>>6)]=sq; }
  __syncthreads();
  float s4=red[0]+red[1]+red[2]+red[3], q4=red[4]+red[5]+red[6]+red[7];
  float mu=s4/768.0f, var=q4/768.0f-mu*mu, inv=rsqrtf(var+EPS_F);
  #pragma unroll
  for (int i=0;i<3;i++){ int cc=t+i*256; xn[cc]=(v[i]-mu)*inv*lnw[cc]; }
  __syncthreads();
  if (t < 246) {
    int cls = t / 6, ch = t % 6;
    const float* wr = outW + (size_t)cls*768 + ch*128;
    const float* xp = xn + ch*128;
    float a = 0;
    for (int k=0;k<128;k++) a += xp[k]*wr[k];
    pb[cls][ch] = a;
  }
  __syncthreads();
  if (t < 41) {
    float a = outb[t];
    #pragma unroll
    for (int ch=0; ch<6; ch++) a += pb[t][ch];
    out[(size_t)row*41 + t] = a;
  }
}

extern "C" void kernel_launch(void* const* d_in, const int* in_sizes, int n_in,
                              void* d_out, int out_size, void* d_ws, size_t ws_size,
                              hipStream_t stream) {
  const float* features = (const float*)d_in[0];
  const int*   didx     = (const int*)d_in[1];
  const float* dayW     = (const float*)d_in[2];
  const float* dayb     = (const float*)d_in[3];
  const float* inW      = (const float*)d_in[4];
  const float* inb      = (const float*)d_in[5];
  const float* lnw      = (const float*)d_in[6];
  const float* convW    = (const float*)d_in[7];
  const float* convb    = (const float*)d_in[8];
  const float* gateW    = (const float*)d_in[9];
  const float* recW     = (const float*)d_in[10];
  const float* cellb    = (const float*)d_in[11];
  const float* gnw      = (const float*)d_in[12];
  const float* plnw     = (const float*)d_in[13];
  const float* outW     = (const float*)d_in[14];
  const float* outb     = (const float*)d_in[15];
  float* out = (float*)d_out;

  auto AL = [](size_t v)->size_t { return (v + 255) & ~255ULL; };

  // persistent buffers
  const size_t GATEWT_B = (size_t)5*4*768*192*2;   // 5.9 MB
  const size_t RECWT_B  = (size_t)20*768*192*2;    // 5.9 MB
  const size_t X_B      = (size_t)8096*768*4;      // 24.9 MB
  const size_t PERSIST  = AL(GATEWT_B) + AL(RECWT_B) + AL(X_B) + AL(2048);

  // choose chunking: merged (1 chunk of 32 batches) if workspace allows,
  // else the verified 2x16 layout (~80.2 MB).
  int nch = 2, bch = 16;
  {
    const size_t uPreM  = AL((size_t)512*512*2) + AL((size_t)768*7168*2)
                        + AL((size_t)32*1024*512*2);
    const size_t xinM   = AL((size_t)32*S_LEN*768*2);
    const size_t uLoopM = xinM*2 + AL((size_t)32*4*S_LEN*768*2) + xinM;
    const size_t uMaxM  = uPreM > uLoopM ? uPreM : uLoopM;
    if (ws_size >= PERSIST + uMaxM + 4096) { nch = 1; bch = 32; }
  }
  const int MCH = bch * S_LEN;              // rows per chunk

  char* ws = (char*)d_ws;
  size_t off = 0;
  auto alloc = [&](size_t bytes)->void* { void* p = ws + off; off += AL(bytes); return p; };
  bf16*     gateWT = (bf16*)alloc(GATEWT_B);
  _Float16* recWT  = (_Float16*)alloc(RECWT_B);
  float*    x      = (float*)alloc(X_B);
  float*    dbsel  = (float*)alloc(2048);
  char*     U      = ws + off;
  // pre-loop carve of U:
  bf16*     dayWT  = (bf16*)U;
  bf16*     inWT   = (bf16*)(U + AL((size_t)512*512*2));
  bf16*     x1     = (bf16*)(U + AL((size_t)512*512*2) + AL((size_t)768*7168*2));
  // loop carve of U:
  const size_t xinB  = (size_t)MCH*768*2;
  const size_t gbufB = (size_t)bch*4*S_LEN*768*2;
  bf16*     xin    = (bf16*)U;
  bf16*     xc     = (bf16*)(U + AL(xinB));
  bf16*     gbuf   = (bf16*)(U + AL(xinB) + AL(xinB));
  bf16*     ybuf   = (bf16*)(U + AL(xinB) + AL(xinB) + AL(gbufB));

  prep_dayb<<<dim3(2), dim3(256), 0, stream>>>(dayb, didx, dbsel);
  transpose_day<<<dim3(16,16), dim3(32,8), 0, stream>>>(dayW, didx, dayWT);
  cvt_inW<<<dim3(5376), dim3(256), 0, stream>>>(inW, inWT);
  transpose_gate<<<dim3(6,6,80), dim3(32,8), 0, stream>>>(gateW, gateWT);
  transpose_rec<<<dim3(24,6,20), dim3(32,8), 0, stream>>>(recW, recWT);

  // day projection + softsign + in_proj, batch-chunked (x1 holds bch batches)
  for (int c = 0; c < nch; c++) {
    gemm_bt_kernel<<<dim3(bch*8, 4, 1), dim3(256), 0, stream>>>(
        features + (size_t)c*bch*1024*512, (const bf16*)nullptr, (const bf16*)nullptr, 512, dayWT,
        (float*)nullptr, x1, dbsel, bch*1024, 512, 512, 0);
    gemm_bt_kernel<<<dim3((MCH+127)/128, 6, 1), dim3(256), 0, stream>>>(
        (const float*)nullptr, x1, (const bf16*)nullptr, 0, inWT,
        x + (size_t)c*MCH*768, (bf16*)nullptr, inb, MCH, 768, 7168, 1);
  }

  for (int l = 0; l < 5; l++) {
    for (int c = 0; c < nch; c++) {
      float* xC = x + (size_t)c*MCH*768;
      ln_kernel  <<<dim3(MCH), dim3(256), 0, stream>>>(xC, lnw + (size_t)l*768, xin);
      conv_kernel<<<dim3(MCH), dim3(256), 0, stream>>>(xin, convW + (size_t)l*768*4, convb + (size_t)l*768, xc);
      gemm_bt_kernel<<<dim3((MCH+127)/128, 3, 8), dim3(256), 0, stream>>>(
          (const float*)nullptr, xc, xin, 768, gateWT + (size_t)l*4*768*192,
          (float*)nullptr, gbuf, (const float*)nullptr, MCH, 384, 192, 2);
      scan_kernel<<<dim3(bch*NHEAD), dim3(768), 0, stream>>>(
          gbuf, recWT + (size_t)l*4*768*192, cellb + (size_t)l*3072, ybuf);
      gn_kernel  <<<dim3(MCH*NHEAD), dim3(64), 0, stream>>>(ybuf, gnw + (size_t)l*768, xC);
    }
  }
  out_kernel<<<dim3(8096), dim3(256), 0, stream>>>(x, plnw, outW, outb, out);
}

// Round 8
// 3091.180 us; speedup vs baseline: 1.0647x; 1.0052x over previous
//
#include <hip/hip_runtime.h>
#include <hip/hip_bf16.h>
#include <stdint.h>

#define S_LEN 253
#define NHEAD 4
#define DHEAD 192
#define EPS_F 1e-5f

typedef __hip_bfloat16 bf16;
using short8  = __attribute__((ext_vector_type(8))) short;
using floatx4 = __attribute__((ext_vector_type(4))) float;
using half2_t = __attribute__((ext_vector_type(2))) _Float16;
typedef unsigned int u32;
typedef unsigned short u16;

__device__ inline float bf2f(bf16 v){ return __bfloat162float(v); }
__device__ inline bf16  f2bf(float v){ return __float2bfloat16(v); }
__device__ inline short f2bfs(float v){ bf16 b = __float2bfloat16(v); return __builtin_bit_cast(short, b); }
__device__ inline float us2f(u16 v){ u32 x = ((u32)v) << 16; return __builtin_bit_cast(float, x); }
__device__ inline half2_t h2(u32 v){ return __builtin_bit_cast(half2_t, v); }

__device__ inline void gll16(const void* g, void* l) {
  __builtin_amdgcn_global_load_lds((const __attribute__((address_space(1))) u32*)g,
                                   (__attribute__((address_space(3))) u32*)l, 16, 0, 0);
}

__device__ inline float fdot2(half2_t a, half2_t b, float c) {
#if __has_builtin(__builtin_amdgcn_fdot2)
  return __builtin_amdgcn_fdot2(a, b, c, false);
#else
  return c + (float)a[0]*(float)b[0] + (float)a[1]*(float)b[1];
#endif
}

// sum across the 4 lanes of a quad (lanes differing in bits 0..1), pure-VALU DPP
__device__ inline float quadsum(float x){
  int xi = __builtin_bit_cast(int, x);
  int a  = __builtin_amdgcn_update_dpp(0, xi, 0xB1, 0xF, 0xF, true);   // quad_perm [1,0,3,2]
  float s1 = x + __builtin_bit_cast(float, a);
  int si = __builtin_bit_cast(int, s1);
  int b  = __builtin_amdgcn_update_dpp(0, si, 0x4E, 0xF, 0xF, true);   // quad_perm [2,3,0,1]
  return s1 + __builtin_bit_cast(float, b);
}

// LDS-only barrier (builtin-only, verified r5): ds_write completion
// (lgkmcnt(0)) -> s_barrier. vmcnt is NOT drained.
// imm 0xC07F: vmcnt=63 (bits[3:0]=0xF,[15:14]=0x3), expcnt=7, lgkmcnt=0.
__device__ inline void lds_barrier(){
  __builtin_amdgcn_s_waitcnt(0xC07F);
  __builtin_amdgcn_s_barrier();
  __builtin_amdgcn_sched_barrier(0);
}

// ---------------- weight prep kernels (all inputs f32) ----------------
__global__ void prep_dayb(const float* __restrict__ db, const int* __restrict__ didx,
                          float* __restrict__ out) {
  int day = didx[0];
  int i = threadIdx.x + blockIdx.x*blockDim.x;
  if (i < 512) out[i] = db[day*512 + i];
}

// day_W[day] (512x512 f32, KxN) -> dayWT bf16 (NxK)
__global__ void transpose_day(const float* __restrict__ dayW, const int* __restrict__ didx,
                              bf16* __restrict__ out) {
  __shared__ float t[32][33];
  int day = didx[0];
  const float* in = dayW + (size_t)day*512*512;
  int c0 = blockIdx.x*32, r0 = blockIdx.y*32;
  int x = threadIdx.x, y = threadIdx.y;
  for (int dy=0; dy<32; dy+=8) t[y+dy][x] = in[(size_t)(r0+y+dy)*512 + c0+x];
  __syncthreads();
  for (int dy=0; dy<32; dy+=8) out[(size_t)(c0+y+dy)*512 + r0+x] = f2bf(t[x][y+dy]);
}

// in_proj_W (768x7168 f32, already NxK) -> bf16
__global__ void cvt_inW(const float* __restrict__ in, bf16* __restrict__ out) {
  size_t i = ((size_t)blockIdx.x*256 + threadIdx.x)*4;
  float4 v = *(const float4*)(in + i);
  out[i+0]=f2bf(v.x); out[i+1]=f2bf(v.y); out[i+2]=f2bf(v.z); out[i+3]=f2bf(v.w);
}

// gate_W (L,4,NH,192,192 f32) [d][e] -> gateWT bf16 [(l,h)][g*192+e][d]
__global__ void transpose_gate(const float* __restrict__ gw, bf16* __restrict__ out) {
  __shared__ float t[32][33];
  int z = blockIdx.z; int l = z>>4, g = (z>>2)&3, h = z&3;
  const float* in = gw + (size_t)z*(192*192);
  bf16* o = out + ((size_t)(l*4+h)*768 + g*192)*192;
  int e0 = blockIdx.x*32, d0 = blockIdx.y*32;
  int x = threadIdx.x, y = threadIdx.y;
  for (int dy=0; dy<32; dy+=8) t[y+dy][x] = in[(size_t)(d0+y+dy)*192 + e0+x];
  __syncthreads();
  for (int dy=0; dy<32; dy+=8) o[(size_t)(e0+y+dy)*192 + d0+x] = f2bf(t[x][y+dy]);
}

// rec_W (L,NH,192,768 f32) [d][(g,e)] -> recWT f16 [(l,h)][(g,e)][d]
__global__ void transpose_rec(const float* __restrict__ rw, _Float16* __restrict__ out) {
  __shared__ float t[32][33];
  int z = blockIdx.z;
  const float* in = rw + (size_t)z*(192*768);
  _Float16* o = out + (size_t)z*(768*192);
  int c0 = blockIdx.x*32, d0 = blockIdx.y*32;
  int x = threadIdx.x, y = threadIdx.y;
  for (int dy=0; dy<32; dy+=8) t[y+dy][x] = in[(size_t)(d0+y+dy)*768 + c0+x];
  __syncthreads();
  for (int dy=0; dy<32; dy+=8) o[(size_t)(c0+y+dy)*192 + d0+x] = (_Float16)t[x][y+dy];
}

// ---------------- GEMM (BT row-major NxK bf16) ----------------
// mode 0: day   (A = Af f32, staged via VALU convert; out bf16, bias f32, softsign)
// mode 1: inproj(A = bf16 patch view of x1 chunk; out f32, bias f32)
// mode 2: gates (A=xc/A2=xin bf16, col offset h*192; out bf16 to [(bl*4+h)][s][768])
__global__ __launch_bounds__(256, 2) void gemm_bt_kernel(
    const float* __restrict__ Af,
    const bf16* __restrict__ A, const bf16* __restrict__ A2, int lda,
    const bf16* __restrict__ BT,
    float* __restrict__ Cf, bf16* __restrict__ Cb,
    const float* __restrict__ biasf,
    int M, int N, int K, int mode)
{
  __shared__ __align__(16) short As[128*32];
  __shared__ __align__(16) short Bs[128*32];

  const int tid  = threadIdx.x;
  const int lane = tid & 63;
  const int wv   = tid >> 6;
  const int quad = lane >> 4;
  const int l16  = lane & 15;

  const int tile_m = blockIdx.x * 128;
  const int tile_n = blockIdx.y * 128;

  const bf16* Abase = A;
  const bf16* BTbase = BT;
  int coloff = 0, hsel = 0;
  if (mode == 2) {
    int z = blockIdx.z;
    hsel = z >> 1;
    int src = z & 1;
    Abase = (src ? A2 : A) + hsel * DHEAD;
    BTbase = BT + (size_t)hsel*(768*192) + (size_t)src*(384*192);
    coloff = src * 384;
  }

  auto arow = [&](int r)->const bf16* {   // bf16 A row (modes 1,2)
    r = min(r, M-1);
    if (mode == 1) { int b = r / S_LEN; int s = r - b*S_LEN;
                     return Abase + (size_t)b*(1024*512) + (size_t)s*2048; }
    return Abase + (size_t)r * lda;
  };

  const bf16  *aptr0=nullptr, *aptr1=nullptr;
  const float *fptr0=nullptr, *fptr1=nullptr;
  if (mode == 0) {
    fptr0 = Af + (size_t)min(tile_m + (tid>>2), M-1)*K + (tid&3)*8;
    fptr1 = Af + (size_t)min(tile_m + 64 + (tid>>2), M-1)*K + (tid&3)*8;
  } else {
    aptr0 = arow(tile_m + (tid>>2)) + (tid&3)*8;
    aptr1 = arow(tile_m + 64 + (tid>>2)) + (tid&3)*8;
  }
  const bf16* bptr0 = BTbase + (size_t)min(tile_n + (tid>>2), N-1)*K + (tid&3)*8;
  const bf16* bptr1 = BTbase + (size_t)min(tile_n + 64 + (tid>>2), N-1)*K + (tid&3)*8;

  short* As0 = As + wv*512;        short* As1 = As + 2048 + wv*512;
  short* Bs0 = Bs + wv*512;        short* Bs1 = Bs + 2048 + wv*512;

  floatx4 acc[4][4];
  #pragma unroll
  for (int i=0;i<4;i++)
    #pragma unroll
    for (int j=0;j<4;j++) acc[i][j] = (floatx4)0.0f;

  const int wm = wv & 1, wn = wv >> 1;
  const int aoff = (wm*64 + l16)*32 + quad*8;
  const int boff = (wn*64 + l16)*32 + quad*8;

  for (int k0 = 0; k0 < K; k0 += 32) {
    if (mode == 0) {
      float4 u0 = *(const float4*)(fptr0 + k0);
      float4 u1 = *(const float4*)(fptr0 + k0 + 4);
      float4 v0 = *(const float4*)(fptr1 + k0);
      float4 v1 = *(const float4*)(fptr1 + k0 + 4);
      short8 sa, sb;
      sa[0]=f2bfs(u0.x); sa[1]=f2bfs(u0.y); sa[2]=f2bfs(u0.z); sa[3]=f2bfs(u0.w);
      sa[4]=f2bfs(u1.x); sa[5]=f2bfs(u1.y); sa[6]=f2bfs(u1.z); sa[7]=f2bfs(u1.w);
      sb[0]=f2bfs(v0.x); sb[1]=f2bfs(v0.y); sb[2]=f2bfs(v0.z); sb[3]=f2bfs(v0.w);
      sb[4]=f2bfs(v1.x); sb[5]=f2bfs(v1.y); sb[6]=f2bfs(v1.z); sb[7]=f2bfs(v1.w);
      *(short8*)(As0 + lane*8) = sa;
      *(short8*)(As1 + lane*8) = sb;
    } else {
      gll16(aptr0 + k0, As0);
      gll16(aptr1 + k0, As1);
    }
    gll16(bptr0 + k0, Bs0);
    gll16(bptr1 + k0, Bs1);
    __syncthreads();
    short8 af[4], bfg[4];
    #pragma unroll
    for (int i=0;i<4;i++) af[i]  = *(const short8*)(As + aoff + i*512);
    #pragma unroll
    for (int j=0;j<4;j++) bfg[j] = *(const short8*)(Bs + boff + j*512);
    #pragma unroll
    for (int i=0;i<4;i++)
      #pragma unroll
      for (int j=0;j<4;j++)
        acc[i][j] = __builtin_amdgcn_mfma_f32_16x16x32_bf16(af[i], bfg[j], acc[i][j], 0,0,0);
    __syncthreads();
  }

  #pragma unroll
  for (int i=0;i<4;i++) {
    int m0 = tile_m + wm*64 + i*16 + quad*4;
    #pragma unroll
    for (int j=0;j<4;j++) {
      int n = tile_n + wn*64 + j*16 + l16;
      if (n >= N) continue;
      #pragma unroll
      for (int r=0;r<4;r++) {
        int row = m0 + r;
        if (row >= M) continue;
        float v = acc[i][j][r];
        if (mode == 0) {
          v += biasf[n];
          v = v / (1.0f + fabsf(v));
          Cb[(size_t)row * N + n] = f2bf(v);
        } else if (mode == 1) {
          v += biasf[n];
          Cf[(size_t)row * N + n] = v;
        } else {
          int bl = row / S_LEN, s = row - bl*S_LEN;
          Cb[((size_t)(bl*NHEAD + hsel)*S_LEN + s)*768 + coloff + n] = f2bf(v);
        }
      }
    }
  }
}

// ---------------- per-row LayerNorm -> bf16 (w f32) ----------------
__global__ __launch_bounds__(256) void ln_kernel(const float* __restrict__ x,
    const float* __restrict__ w, bf16* __restrict__ out) {
  int row = blockIdx.x, t = threadIdx.x;
  const float* xr = x + (size_t)row*768;
  float v[3]; float s = 0, sq = 0;
  #pragma unroll
  for (int i=0;i<3;i++){ v[i] = xr[t + i*256]; s += v[i]; sq += v[i]*v[i]; }
  __shared__ float rs[4], rq[4];
  for (int off=32; off>0; off>>=1){ s += __shfl_down(s,off); sq += __shfl_down(sq,off); }
  if ((t&63)==0){ rs[t>>6]=s; rq[t>>6]=sq; }
  __syncthreads();
  float s4 = rs[0]+rs[1]+rs[2]+rs[3], q4 = rq[0]+rq[1]+rq[2]+rq[3];
  float mu = s4/768.0f, var = q4/768.0f - mu*mu, inv = rsqrtf(var + EPS_F);
  #pragma unroll
  for (int i=0;i<3;i++){ int c = t + i*256;
    out[(size_t)row*768 + c] = f2bf((v[i]-mu)*inv*w[c]); }
}

// ---------------- causal depthwise conv K=4 + SiLU (W,b f32) ----------------
__global__ __launch_bounds__(256) void conv_kernel(const bf16* __restrict__ xin,
    const float* __restrict__ W, const float* __restrict__ bias, bf16* __restrict__ out) {
  int row = blockIdx.x; int b = row / S_LEN; int s = row - b*S_LEN;
  int t = threadIdx.x;
  #pragma unroll
  for (int i=0;i<3;i++){
    int d = t + i*256;
    float acc = bias[d];
    #pragma unroll
    for (int k=0;k<4;k++){
      int ss = s - 3 + k;
      if (ss >= 0) acc += W[d*4+k] * bf2f(xin[((size_t)b*S_LEN + ss)*768 + d]);
    }
    float sg = 1.0f/(1.0f + __expf(-acc));
    out[(size_t)row*768 + d] = f2bf(acc * sg);
  }
}

// ---------------- sLSTM scan v4f: quad-split + occupancy-clamped R residency --
// Identical to verified v4c/v4e except amdgpu_waves_per_eu(3,3).
// r7 evidence: VGPR_Count stayed 64 (= 512/8) under __launch_bounds__(768,3) —
// the scheduler targets 8 waves/SIMD on its own and re-fetches the 96-reg Rc
// array from L2 every step (the session-long hidden cost: ~288KB/step/block).
// min=max=3 waves/EU clamps the occupancy TARGET, raising the pressure budget
// to 512/3=170 so Rc (96) + working set (~45) stays VGPR-resident.
__global__ __launch_bounds__(768) __attribute__((amdgpu_waves_per_eu(3, 3)))
void scan_kernel(
    const bf16* __restrict__ gates, const _Float16* __restrict__ recWT,
    const float* __restrict__ cellb, bf16* __restrict__ y)
{
  const int bh = blockIdx.x; const int bl = bh >> 2, h = bh & 3;
  const int tid  = threadIdx.x;
  const int w    = tid >> 6;
  const int lane = tid & 63;
  const int q    = lane & 3;
  const int r    = lane >> 2;
  const int e    = w*16 + r;
  const int nl   = q*192 + e;          // column whose gate/bias this lane injects

  // R fragments: for g=0..3, chunk q (48 f16) of column g*192+e -> 24 u32 each
  u32 Rc[4][24];
  {
    const _Float16* rbase = recWT + (size_t)h*768*192;
    #pragma unroll
    for (int g=0; g<4; g++){
      const uint4* rp = (const uint4*)(rbase + (size_t)(g*192 + e)*192 + q*48);
      #pragma unroll
      for (int j=0;j<6;j++){ uint4 v = rp[j];
        Rc[g][4*j]=v.x; Rc[g][4*j+1]=v.y; Rc[g][4*j+2]=v.z; Rc[g][4*j+3]=v.w; }
    }
  }
  const float bias = cellb[h*768 + nl];
  const bf16* gb = gates + (size_t)bh*S_LEN*768 + nl;

  __shared__ __align__(16) _Float16 hbuf[2][192];
  if (tid < 96) ((u32*)&hbuf[0][0])[tid] = 0;

  float cst = 0.0f, nst = 0.0f, mst = 0.0f;
  float ga = us2f(*(const u16*)gb);
  __syncthreads();

  for (int s = 0; s < S_LEN; s++) {
    float inj = ga + bias;
    if (s + 1 < S_LEN) ga = us2f(*(const u16*)(gb + (size_t)(s+1)*768));

    float p0 = (q==0) ? inj : 0.0f;
    float p1 = (q==1) ? inj : 0.0f;
    float p2 = (q==2) ? inj : 0.0f;
    float p3 = (q==3) ? inj : 0.0f;

    const uint4* hb = (const uint4*)((const char*)&hbuf[s & 1][0] + q*96);
    #pragma unroll
    for (int j=0;j<6;j++) {
      uint4 hv = hb[j];
      p0 = fdot2(h2(hv.x), h2(Rc[0][4*j+0]), p0);
      p0 = fdot2(h2(hv.y), h2(Rc[0][4*j+1]), p0);
      p0 = fdot2(h2(hv.z), h2(Rc[0][4*j+2]), p0);
      p0 = fdot2(h2(hv.w), h2(Rc[0][4*j+3]), p0);
      p1 = fdot2(h2(hv.x), h2(Rc[1][4*j+0]), p1);
      p1 = fdot2(h2(hv.y), h2(Rc[1][4*j+1]), p1);
      p1 = fdot2(h2(hv.z), h2(Rc[1][4*j+2]), p1);
      p1 = fdot2(h2(hv.w), h2(Rc[1][4*j+3]), p1);
      p2 = fdot2(h2(hv.x), h2(Rc[2][4*j+0]), p2);
      p2 = fdot2(h2(hv.y), h2(Rc[2][4*j+1]), p2);
      p2 = fdot2(h2(hv.z), h2(Rc[2][4*j+2]), p2);
      p2 = fdot2(h2(hv.w), h2(Rc[2][4*j+3]), p2);
      p3 = fdot2(h2(hv.x), h2(Rc[3][4*j+0]), p3);
      p3 = fdot2(h2(hv.y), h2(Rc[3][4*j+1]), p3);
      p3 = fdot2(h2(hv.z), h2(Rc[3][4*j+2]), p3);
      p3 = fdot2(h2(hv.w), h2(Rc[3][4*j+3]), p3);
    }

    // complete the 192-deep dots across the quad; afterwards every lane of the
    // quad holds all four gate raws for its e (i,f,z,o), injection included.
    float iraw = quadsum(p0);
    float fraw = quadsum(p1);
    float zraw = quadsum(p2);
    float oraw = quadsum(p3);

    float lsig = fminf(fraw, 0.0f) - log1pf(__expf(-fabsf(fraw)));
    float lfpm = mst + lsig;
    float mnew = (s == 0) ? iraw : fmaxf(iraw, lfpm);
    float ig = __expf(iraw - mnew);
    float e2z = __expf(2.0f * zraw);
    float tz = 1.0f - 2.0f/(e2z + 1.0f);
    float cnew, nnew;
    if (s == 0) { cnew = ig*tz; nnew = ig; }
    else {
      float fg = __expf(lfpm - mnew);
      cnew = fg*cst + ig*tz; nnew = fg*nst + ig;
    }
    float sg = 1.0f/(1.0f + __expf(-oraw));
    float yv = sg * cnew / nnew;
    cst = cnew; nst = nnew; mst = mnew;

    if (q == 0) {
      hbuf[(s+1)&1][e] = (_Float16)yv;
      y[((size_t)bl*S_LEN + s)*768 + h*DHEAD + e] = f2bf(yv);
    }
    lds_barrier();
  }
}

// ---------------- GroupNorm over DH + residual into x (y bf16, w f32) ----------------
__global__ __launch_bounds__(64) void gn_kernel(const bf16* __restrict__ y,
    const float* __restrict__ w, float* __restrict__ x) {
  int rg = blockIdx.x;
  int row = rg >> 2, h = rg & 3;
  int t = threadIdx.x;
  const bf16* yr = y + (size_t)row*768 + h*DHEAD;
  float v0 = bf2f(yr[t]), v1 = bf2f(yr[t+64]), v2 = bf2f(yr[t+128]);
  float s = v0+v1+v2, sq = v0*v0+v1*v1+v2*v2;
  for (int off=32; off>0; off>>=1){ s += __shfl_down(s,off); sq += __shfl_down(sq,off); }
  s = __shfl(s, 0); sq = __shfl(sq, 0);
  float mu = s/192.0f, var = sq/192.0f - mu*mu, inv = rsqrtf(var + EPS_F);
  float* xr = x + (size_t)row*768 + h*DHEAD;
  xr[t]     += (v0-mu)*inv*w[h*DHEAD+t];
  xr[t+64]  += (v1-mu)*inv*w[h*DHEAD+t+64];
  xr[t+128] += (v2-mu)*inv*w[h*DHEAD+t+128];
}

// ---------------- post-LN + out projection (N=41), all f32 ----------------
__global__ __launch_bounds__(256) void out_kernel(const float* __restrict__ x,
    const float* __restrict__ lnw, const float* __restrict__ outW,
    const float* __restrict__ outb, float* __restrict__ out) {
  __shared__ float xn[768];
  __shared__ float red[8];
  __shared__ float pb[41][6];
  int row = blockIdx.x, t = threadIdx.x;
  const float* xr = x + (size_t)row*768;
  float v[3]; float s = 0, sq = 0;
  #pragma unroll
  for (int i=0;i<3;i++){ v[i]=xr[t+i*256]; s+=v[i]; sq+=v[i]*v[i]; }
  for (int off=32; off>0; off>>=1){ s+=__shfl_down(s,off); sq+=__shfl_down(sq,off); }
  if ((t&63)==0){ red[t>>6]=s; red[4+(t>>6)]=sq; }
  __syncthreads();
  float s4=red[0]+red[1]+red[2]+red[3], q4=red[4]+red[5]+red[6]+red[7];
  float mu=s4/768.0f, var=q4/768.0f-mu*mu, inv=rsqrtf(var+EPS_F);
  #pragma unroll
  for (int i=0;i<3;i++){ int cc=t+i*256; xn[cc]=(v[i]-mu)*inv*lnw[cc]; }
  __syncthreads();
  if (t < 246) {
    int cls = t / 6, ch = t % 6;
    const float* wr = outW + (size_t)cls*768 + ch*128;
    const float* xp = xn + ch*128;
    float a = 0;
    for (int k=0;k<128;k++) a += xp[k]*wr[k];
    pb[cls][ch] = a;
  }
  __syncthreads();
  if (t < 41) {
    float a = outb[t];
    #pragma unroll
    for (int ch=0; ch<6; ch++) a += pb[t][ch];
    out[(size_t)row*41 + t] = a;
  }
}

extern "C" void kernel_launch(void* const* d_in, const int* in_sizes, int n_in,
                              void* d_out, int out_size, void* d_ws, size_t ws_size,
                              hipStream_t stream) {
  const float* features = (const float*)d_in[0];
  const int*   didx     = (const int*)d_in[1];
  const float* dayW     = (const float*)d_in[2];
  const float* dayb     = (const float*)d_in[3];
  const float* inW      = (const float*)d_in[4];
  const float* inb      = (const float*)d_in[5];
  const float* lnw      = (const float*)d_in[6];
  const float* convW    = (const float*)d_in[7];
  const float* convb    = (const float*)d_in[8];
  const float* gateW    = (const float*)d_in[9];
  const float* recW     = (const float*)d_in[10];
  const float* cellb    = (const float*)d_in[11];
  const float* gnw      = (const float*)d_in[12];
  const float* plnw     = (const float*)d_in[13];
  const float* outW     = (const float*)d_in[14];
  const float* outb     = (const float*)d_in[15];
  float* out = (float*)d_out;

  auto AL = [](size_t v)->size_t { return (v + 255) & ~255ULL; };

  // persistent buffers
  const size_t GATEWT_B = (size_t)5*4*768*192*2;   // 5.9 MB
  const size_t RECWT_B  = (size_t)20*768*192*2;    // 5.9 MB
  const size_t X_B      = (size_t)8096*768*4;      // 24.9 MB
  const size_t PERSIST  = AL(GATEWT_B) + AL(RECWT_B) + AL(X_B) + AL(2048);

  // choose chunking: merged (1 chunk of 32 batches) if workspace allows,
  // else the verified 2x16 layout (~80.2 MB).
  int nch = 2, bch = 16;
  {
    const size_t uPreM  = AL((size_t)512*512*2) + AL((size_t)768*7168*2)
                        + AL((size_t)32*1024*512*2);
    const size_t xinM   = AL((size_t)32*S_LEN*768*2);
    const size_t uLoopM = xinM*2 + AL((size_t)32*4*S_LEN*768*2) + xinM;
    const size_t uMaxM  = uPreM > uLoopM ? uPreM : uLoopM;
    if (ws_size >= PERSIST + uMaxM + 4096) { nch = 1; bch = 32; }
  }
  const int MCH = bch * S_LEN;              // rows per chunk

  char* ws = (char*)d_ws;
  size_t off = 0;
  auto alloc = [&](size_t bytes)->void* { void* p = ws + off; off += AL(bytes); return p; };
  bf16*     gateWT = (bf16*)alloc(GATEWT_B);
  _Float16* recWT  = (_Float16*)alloc(RECWT_B);
  float*    x      = (float*)alloc(X_B);
  float*    dbsel  = (float*)alloc(2048);
  char*     U      = ws + off;
  // pre-loop carve of U:
  bf16*     dayWT  = (bf16*)U;
  bf16*     inWT   = (bf16*)(U + AL((size_t)512*512*2));
  bf16*     x1     = (bf16*)(U + AL((size_t)512*512*2) + AL((size_t)768*7168*2));
  // loop carve of U:
  const size_t xinB  = (size_t)MCH*768*2;
  const size_t gbufB = (size_t)bch*4*S_LEN*768*2;
  bf16*     xin    = (bf16*)U;
  bf16*     xc     = (bf16*)(U + AL(xinB));
  bf16*     gbuf   = (bf16*)(U + AL(xinB) + AL(xinB));
  bf16*     ybuf   = (bf16*)(U + AL(xinB) + AL(xinB) + AL(gbufB));

  prep_dayb<<<dim3(2), dim3(256), 0, stream>>>(dayb, didx, dbsel);
  transpose_day<<<dim3(16,16), dim3(32,8), 0, stream>>>(dayW, didx, dayWT);
  cvt_inW<<<dim3(5376), dim3(256), 0, stream>>>(inW, inWT);
  transpose_gate<<<dim3(6,6,80), dim3(32,8), 0, stream>>>(gateW, gateWT);
  transpose_rec<<<dim3(24,6,20), dim3(32,8), 0, stream>>>(recW, recWT);

  // day projection + softsign + in_proj, batch-chunked (x1 holds bch batches)
  for (int c = 0; c < nch; c++) {
    gemm_bt_kernel<<<dim3(bch*8, 4, 1), dim3(256), 0, stream>>>(
        features + (size_t)c*bch*1024*512, (const bf16*)nullptr, (const bf16*)nullptr, 512, dayWT,
        (float*)nullptr, x1, dbsel, bch*1024, 512, 512, 0);
    gemm_bt_kernel<<<dim3((MCH+127)/128, 6, 1), dim3(256), 0, stream>>>(
        (const float*)nullptr, x1, (const bf16*)nullptr, 0, inWT,
        x + (size_t)c*MCH*768, (bf16*)nullptr, inb, MCH, 768, 7168, 1);
  }

  for (int l = 0; l < 5; l++) {
    for (int c = 0; c < nch; c++) {
      float* xC = x + (size_t)c*MCH*768;
      ln_kernel  <<<dim3(MCH), dim3(256), 0, stream>>>(xC, lnw + (size_t)l*768, xin);
      conv_kernel<<<dim3(MCH), dim3(256), 0, stream>>>(xin, convW + (size_t)l*768*4, convb + (size_t)l*768, xc);
      gemm_bt_kernel<<<dim3((MCH+127)/128, 3, 8), dim3(256), 0, stream>>>(
          (const float*)nullptr, xc, xin, 768, gateWT + (size_t)l*4*768*192,
          (float*)nullptr, gbuf, (const float*)nullptr, MCH, 384, 192, 2);
      scan_kernel<<<dim3(bch*NHEAD), dim3(768), 0, stream>>>(
          gbuf, recWT + (size_t)l*4*768*192, cellb + (size_t)l*3072, ybuf);
      gn_kernel  <<<dim3(MCH*NHEAD), dim3(64), 0, stream>>>(ybuf, gnw + (size_t)l*768, xC);
    }
  }
  out_kernel<<<dim3(8096), dim3(256), 0, stream>>>(x, plnw, outW, outb, out);
}